// Round 5
// baseline (266.034 us; speedup 1.0000x reference)
//
#include <hip/hip_runtime.h>
#include <hip/hip_bf16.h>
#include <cstdint>
#include <cstddef>

#define AS1 __attribute__((address_space(1)))
#define AS3 __attribute__((address_space(3)))

typedef __bf16 bf16;
typedef __bf16 bf16x8 __attribute__((ext_vector_type(8)));
typedef float f32x4 __attribute__((ext_vector_type(4)));

static constexpr int M_ROWS = 4096;
static constexpr int N_COLS = 1024;
static constexpr int IN_F   = 1024;
static constexpr int K2     = IN_F * 9;   // 9216: [silu(x) | 8 bases per i]
static constexpr int BK     = 32;         // fallback K-step
static constexpr int KT_CNT = K2 / BK;    // 288 (fallback)

static constexpr int GBK = 64;            // gemm K-step: rows are 128 B = 32 banks
static constexpr int GKT = K2 / GBK;      // 144

// Interface (R8 beacon): inputs f32, dict order, sizes in elements, out f32.

// Closed-form cardinal cubic B-spline over uniform knots t[j] = -2.2 + 0.4*j.
__device__ __forceinline__ void bases8(float x, float w8[8]) {
  float mf = x * 2.5f + 5.5f;           // (x - t0) / h
  int   m  = (int)floorf(mf);
  float u  = mf - (float)m;
  float u2 = u * u, u3 = u2 * u;
  float omu = 1.0f - u;
  const float s = 1.0f / 6.0f;
  float p0 = u3 * s;
  float p1 = (-3.f*u3 + 3.f*u2 + 3.f*u + 1.f) * s;
  float p2 = (3.f*u3 - 6.f*u2 + 4.f) * s;
  float p3 = omu * omu * omu * s;
  bool in = (m >= 0) && (m < 11);
#pragma unroll
  for (int j = 0; j < 8; ++j) {
    float v = 0.0f;
    v = (j == m)     ? p0 : v;
    v = (j == m - 1) ? p1 : v;
    v = (j == m - 2) ? p2 : v;
    v = (j == m - 3) ? p3 : v;
    w8[j] = in ? v : 0.0f;
  }
}

__device__ __forceinline__ void expand_body(const float* __restrict__ x,
                                            bf16* __restrict__ A, int gid, int r0) {
  int b = gid >> 10;
  int i = gid & 1023;
  float xv = x[(size_t)r0 * IN_F + (size_t)gid];
  A[(size_t)b * K2 + i] = (bf16)(xv / (1.0f + __expf(-xv)));
  float w8[8];
  bases8(xv, w8);
  bf16x8 outv;
#pragma unroll
  for (int j = 0; j < 8; ++j) outv[j] = (bf16)w8[j];
  *(bf16x8*)(A + (size_t)b * K2 + IN_F + (size_t)i * 8) = outv;
}

__device__ __forceinline__ void makebt_body(const float* __restrict__ bw,
                                            const float* __restrict__ sw,
                                            const float* __restrict__ sc,
                                            bf16* __restrict__ BT, int gid) {
  int o = gid >> 10;
  int i = gid & 1023;
  BT[(size_t)o * K2 + i] = (bf16)bw[gid];
  float scale = sc[gid];
  const float4* swp = (const float4*)(sw + (size_t)gid * 8);
  float4 a = swp[0], b4 = swp[1];
  float wv[8] = {a.x, a.y, a.z, a.w, b4.x, b4.y, b4.z, b4.w};
  bf16x8 r;
#pragma unroll
  for (int j = 0; j < 8; ++j) r[j] = (bf16)(wv[j] * scale);
  *(bf16x8*)(BT + (size_t)o * K2 + IN_F + (size_t)i * 8) = r;
}

// ---------------------------------------------------------------------------
// Kernel 1 (fused prep): blocks [0,16384) expand A; [16384,20480) build BT.
// ---------------------------------------------------------------------------
__global__ void prep(const float* __restrict__ x, const float* __restrict__ bw,
                     const float* __restrict__ sw, const float* __restrict__ sc,
                     bf16* __restrict__ A, bf16* __restrict__ BT) {
  int bid = blockIdx.x;
  if (bid < (M_ROWS * IN_F) / 256) {
    expand_body(x, A, bid * 256 + threadIdx.x, 0);
  } else {
    makebt_body(bw, sw, sc, BT, (bid - (M_ROWS * IN_F) / 256) * 256 + threadIdx.x);
  }
}

// Standalone versions for the slab fallback path.
__global__ void expand_a(const float* __restrict__ x, bf16* __restrict__ A, int r0) {
  expand_body(x, A, blockIdx.x * blockDim.x + threadIdx.x, r0);
}
__global__ void make_bt(const float* __restrict__ bw, const float* __restrict__ sw,
                        const float* __restrict__ sc, bf16* __restrict__ BT) {
  makebt_body(bw, sw, sc, BT, blockIdx.x * blockDim.x + threadIdx.x);
}

// ---------------------------------------------------------------------------
// Kernel 3 (R16): phase-PIPELINED 256x256 GEMM.
// R15 measured 5370 cy/K-tile = serial sum of {MFMA 2483, ds_read 2304,
// stage 512, barriers} because each phase drained lgkmcnt(0) before its own
// MFMA — reads never overlapped compute. R16 issues each fragment set ONE
// PHASE EARLY with COUNTED lgkm waits (T4 applied to lgkm, not just vmcnt):
//   quadrants: Q0(af03,bf01) Q1(af03,bf23) Q2(af47,bf23) Q3(af47,bf01)
//   P0: issue bf23(4);  stage A-hi(t+1); lgkmcnt(4); bar; Q0
//   P1: issue af47(8);  stage B-lo(t+1); lgkmcnt(8); bar; Q1
//   P2: (no reads);     stage B-hi(t+1); lgkmcnt(0); bar; Q2
//   P3: stage A-lo(t+2) into buf; vmcnt(2); bar; issue af03,bf01(12) from
//       nbuf (drain under Q3+P0-wait); Q3
// Every lgkm wait precedes its barrier -> cross-wave WAR on restaged LDS
// regions is fenced (each region restage is >=1 barrier after its readers'
// completion-wait; verified per region). bf01 register-double-buffered
// (written at P3 while Q3 reads old copy) via x2-unrolled loop with swapped
// array refs; af03/af47/bf23 have disjoint live ranges (single buffer).
// 4 barriers/K-tile (was 8). Geometry/swizzle/split-K/XCD map: R14/R15
// verbatim (conflicts=0 measured).
// ---------------------------------------------------------------------------
__global__ __launch_bounds__(512, 2) void gemm256_pl(
    const bf16* __restrict__ A, const bf16* __restrict__ BT,
    float* __restrict__ P, int kt_seg) {
  __shared__ bf16 As[2][256 * GBK];   // 2 x 32 KB
  __shared__ bf16 Bs[2][256 * GBK];   // 2 x 32 KB  (128 KB)

  const int tid  = threadIdx.x;
  const int lane = tid & 63;
  const int w    = tid >> 6;          // 0..7

  const int b     = blockIdx.x;
  const int mtile = b & 15;           // XCD = b&7 = mtile&7 -> A pinned
  const int np    = (b >> 4) & 3;
  const int seg   = b >> 6;
  const int row0  = mtile * 256;
  const int col0  = np * 256;
  const int kt0   = seg * kt_seg;
  float* __restrict__ dst = P + (size_t)seg * M_ROWS * N_COLS;

  // Staging swizzle (R12-R15 proven): lane l covers (row l>>3, lds chunk l&7);
  // source chunk (l&7)^(l>>3) -> LDS chunk j of row R holds global chunk j^(R&7).
  const int srow = lane >> 3;
  const int sch  = ((lane & 7) ^ srow) * 8;

  const int r  = lane & 15;
  const int q  = lane >> 4;
  const int wm = (w >> 2) * 128;
  const int wn = (w & 3) * 64;
  const int kc0 = ((0 + q) ^ (r & 7)) * 8;   // logical chunk kk*4+q, ^(row&7)
  const int kc1 = ((4 + q) ^ (r & 7)) * 8;

  const bf16* aB = A  + (size_t)row0 * K2;
  const bf16* bB = BT + (size_t)col0 * K2;

  f32x4 acc[8][4];
#pragma unroll
  for (int mt = 0; mt < 8; ++mt)
#pragma unroll
    for (int nt = 0; nt < 4; ++nt)
      acc[mt][nt] = f32x4{0.f, 0.f, 0.f, 0.f};

  // Fragment registers. bf01 double-buffered (A/B roles swap per tile parity).
  bf16x8 af03[4][2], af47[4][2], bf23[2][2], bf01A[2][2], bf01B[2][2];

  auto stageA = [&](int sbuf, int h, int kt) {
#pragma unroll
    for (int t8 = 0; t8 < 2; ++t8) {
      const int rg = h * 128 + w * 16 + t8 * 8;
      const bf16* ga = aB + (size_t)(rg + srow) * K2 + kt * GBK + sch;
      __builtin_amdgcn_global_load_lds((const AS1 void*)ga,
                                       (AS3 void*)&As[sbuf][rg * GBK], 16, 0, 0);
    }
  };
  auto stageB = [&](int sbuf, int h, int kt) {
#pragma unroll
    for (int t8 = 0; t8 < 2; ++t8) {
      const int rg = h * 128 + w * 16 + t8 * 8;
      const bf16* gb = bB + (size_t)(rg + srow) * K2 + kt * GBK + sch;
      __builtin_amdgcn_global_load_lds((const AS1 void*)gb,
                                       (AS3 void*)&Bs[sbuf][rg * GBK], 16, 0, 0);
    }
  };

  auto readA03 = [&](const bf16* src) {
#pragma unroll
    for (int j = 0; j < 4; ++j) {
      const bf16* ar = &src[(wm + j * 16 + r) * GBK];
      af03[j][0] = *(const bf16x8*)&ar[kc0];
      af03[j][1] = *(const bf16x8*)&ar[kc1];
    }
  };
  auto readA47 = [&](const bf16* src) {
#pragma unroll
    for (int j = 0; j < 4; ++j) {
      const bf16* ar = &src[(wm + (4 + j) * 16 + r) * GBK];
      af47[j][0] = *(const bf16x8*)&ar[kc0];
      af47[j][1] = *(const bf16x8*)&ar[kc1];
    }
  };
  auto readB23 = [&](const bf16* src) {
#pragma unroll
    for (int j = 0; j < 2; ++j) {
      const bf16* br = &src[(wn + (2 + j) * 16 + r) * GBK];
      bf23[j][0] = *(const bf16x8*)&br[kc0];
      bf23[j][1] = *(const bf16x8*)&br[kc1];
    }
  };
  auto readB01 = [&](bf16x8 (&dstf)[2][2], const bf16* src) {
#pragma unroll
    for (int j = 0; j < 2; ++j) {
      const bf16* br = &src[(wn + j * 16 + r) * GBK];
      dstf[j][0] = *(const bf16x8*)&br[kc0];
      dstf[j][1] = *(const bf16x8*)&br[kc1];
    }
  };

  // One K-tile, 4 phases. bfc = bf01 for THIS tile; bfn = bf01 for next.
  auto tile_body = [&](int t, int nb, const bf16* as, const bf16* bs,
                       const bf16* nas, const bf16* nbs,
                       bf16x8 (&bfc)[2][2], bf16x8 (&bfn)[2][2]) {
    const bool sN = (t + 1 < kt_seg);

    // -- P0: issue bf23 (this tile); stage A-hi(t+1); wait af03/bf01; Q0 --
    readB23(bs);
    if (sN) stageA(nb, 1, kt0 + t + 1);
    asm volatile("s_waitcnt lgkmcnt(4)" ::: "memory");
    __builtin_amdgcn_sched_barrier(0);
    __builtin_amdgcn_s_barrier();
    __builtin_amdgcn_s_setprio(1);
#pragma unroll
    for (int j = 0; j < 4; ++j)
#pragma unroll
      for (int n = 0; n < 2; ++n) {
        acc[j][n] = __builtin_amdgcn_mfma_f32_16x16x32_bf16(af03[j][0], bfc[n][0], acc[j][n], 0, 0, 0);
        acc[j][n] = __builtin_amdgcn_mfma_f32_16x16x32_bf16(af03[j][1], bfc[n][1], acc[j][n], 0, 0, 0);
      }
    __builtin_amdgcn_s_setprio(0);

    // -- P1: issue af47; stage B-lo(t+1); wait bf23; Q1 --
    readA47(as);
    if (sN) stageB(nb, 0, kt0 + t + 1);
    asm volatile("s_waitcnt lgkmcnt(8)" ::: "memory");
    __builtin_amdgcn_sched_barrier(0);
    __builtin_amdgcn_s_barrier();
    __builtin_amdgcn_s_setprio(1);
#pragma unroll
    for (int j = 0; j < 4; ++j)
#pragma unroll
      for (int n = 0; n < 2; ++n) {
        acc[j][2 + n] = __builtin_amdgcn_mfma_f32_16x16x32_bf16(af03[j][0], bf23[n][0], acc[j][2 + n], 0, 0, 0);
        acc[j][2 + n] = __builtin_amdgcn_mfma_f32_16x16x32_bf16(af03[j][1], bf23[n][1], acc[j][2 + n], 0, 0, 0);
      }
    __builtin_amdgcn_s_setprio(0);

    // -- P2: no reads; stage B-hi(t+1); wait af47; Q2 --
    if (sN) stageB(nb, 1, kt0 + t + 1);
    asm volatile("s_waitcnt lgkmcnt(0)" ::: "memory");
    __builtin_amdgcn_sched_barrier(0);
    __builtin_amdgcn_s_barrier();
    __builtin_amdgcn_s_setprio(1);
#pragma unroll
    for (int j = 0; j < 4; ++j)
#pragma unroll
      for (int n = 0; n < 2; ++n) {
        acc[4 + j][2 + n] = __builtin_amdgcn_mfma_f32_16x16x32_bf16(af47[j][0], bf23[n][0], acc[4 + j][2 + n], 0, 0, 0);
        acc[4 + j][2 + n] = __builtin_amdgcn_mfma_f32_16x16x32_bf16(af47[j][1], bf23[n][1], acc[4 + j][2 + n], 0, 0, 0);
      }
    __builtin_amdgcn_s_setprio(0);

    // -- P3: stage A-lo(t+2) into buf; vmcnt; bar; issue next af03/bf01; Q3 --
    if (t + 2 < kt_seg) stageA(nb ^ 1, 0, kt0 + t + 2);
    if (sN) {
      if (t + 2 < kt_seg) asm volatile("s_waitcnt vmcnt(2)" ::: "memory");
      else                asm volatile("s_waitcnt vmcnt(0)" ::: "memory");
    }
    __builtin_amdgcn_s_barrier();
    if (sN) {
      readA03(nas);
      readB01(bfn, nbs);
    }
    __builtin_amdgcn_sched_barrier(0);
    __builtin_amdgcn_s_setprio(1);
#pragma unroll
    for (int j = 0; j < 4; ++j)
#pragma unroll
      for (int n = 0; n < 2; ++n) {
        acc[4 + j][n] = __builtin_amdgcn_mfma_f32_16x16x32_bf16(af47[j][0], bfc[n][0], acc[4 + j][n], 0, 0, 0);
        acc[4 + j][n] = __builtin_amdgcn_mfma_f32_16x16x32_bf16(af47[j][1], bfc[n][1], acc[4 + j][n], 0, 0, 0);
      }
    __builtin_amdgcn_s_setprio(0);
  };

  // Prologue: tile0 fully + tile1's A-lo; then first af03/bf01 reads.
  stageA(0, 0, kt0); stageA(0, 1, kt0);
  stageB(0, 0, kt0); stageB(0, 1, kt0);
  if (kt_seg > 1) {
    stageA(1, 0, kt0 + 1);
    asm volatile("s_waitcnt vmcnt(2)" ::: "memory");
  } else {
    asm volatile("s_waitcnt vmcnt(0)" ::: "memory");
  }
  __builtin_amdgcn_s_barrier();
  readA03(As[0]);
  readB01(bf01A, Bs[0]);

  // kt_seg is even for all launch configs of this path (36/48/72).
  for (int tt = 0; tt < kt_seg; tt += 2) {
    tile_body(tt,     1, As[0], Bs[0], As[1], Bs[1], bf01A, bf01B);
    tile_body(tt + 1, 0, As[1], Bs[1], As[0], Bs[0], bf01B, bf01A);
  }

  // f32 epilogue: C/D layout col = lane&15, row = (lane>>4)*4 + reg
#pragma unroll
  for (int mt = 0; mt < 8; ++mt)
#pragma unroll
    for (int nt = 0; nt < 4; ++nt)
#pragma unroll
      for (int k = 0; k < 4; ++k) {
        int row = row0 + wm + mt * 16 + q * 4 + k;
        int col = col0 + wn + nt * 16 + r;
        dst[(size_t)row * N_COLS + col] = acc[mt][nt][k];
      }
}

// ---------------------------------------------------------------------------
// Kernel 3b (R13's 128x128 gemm, kept for fallback slab path).
// ---------------------------------------------------------------------------
__global__ __launch_bounds__(256, 2) void gemm_fused(
    const bf16* __restrict__ A, const bf16* __restrict__ BT,
    float* __restrict__ d0, float* __restrict__ d1,
    int r0, int mt_cnt, int kt_seg) {
  __shared__ bf16 As[2][128 * GBK];
  __shared__ bf16 Bs[2][128 * GBK];

  const int tid  = threadIdx.x;
  const int lane = tid & 63;
  const int w    = tid >> 6;

  const int bps = mt_cnt * 8;
  int b   = blockIdx.x;
  const int seg = b / bps;
  b -= seg * bps;
  const int row0 = (b % mt_cnt) * 128;
  const int col0 = (b / mt_cnt) * 128;
  float* __restrict__ dst = seg ? d1 : d0;
  const int kt0 = seg * kt_seg;

  const int srow = lane >> 3;
  const int sch  = ((lane & 7) ^ srow) * 8;
  const int r  = lane & 15;
  const int q  = lane >> 4;
  const int wm = (w >> 1) * 64;
  const int wn = (w & 1) * 64;
  const int kc0 = ((0 + q) ^ (r & 7)) * 8;
  const int kc1 = ((4 + q) ^ (r & 7)) * 8;

  const bf16* aB = A  + (size_t)row0 * K2;
  const bf16* bB = BT + (size_t)col0 * K2;

  f32x4 acc[4][4];
#pragma unroll
  for (int mt = 0; mt < 4; ++mt)
#pragma unroll
    for (int nt = 0; nt < 4; ++nt)
      acc[mt][nt] = f32x4{0.f, 0.f, 0.f, 0.f};

  auto stage = [&](int sbuf, int kt) {
#pragma unroll
    for (int t = 0; t < 4; ++t) {
      const int rg = w * 32 + t * 8;
      const bf16* ga = aB + (size_t)(rg + srow) * K2 + kt * GBK + sch;
      __builtin_amdgcn_global_load_lds((const AS1 void*)ga,
                                       (AS3 void*)&As[sbuf][rg * GBK], 16, 0, 0);
      const bf16* gb = bB + (size_t)(rg + srow) * K2 + kt * GBK + sch;
      __builtin_amdgcn_global_load_lds((const AS1 void*)gb,
                                       (AS3 void*)&Bs[sbuf][rg * GBK], 16, 0, 0);
    }
  };

  stage(0, kt0);
  int buf = 0;
  for (int i = 0; i < kt_seg; ++i) {
    if (i + 1 < kt_seg) {
      stage(buf ^ 1, kt0 + i + 1);
      asm volatile("s_waitcnt vmcnt(8)" ::: "memory");
    } else {
      asm volatile("s_waitcnt vmcnt(0)" ::: "memory");
    }
    __builtin_amdgcn_s_barrier();
    __builtin_amdgcn_sched_barrier(0);

    const bf16* as = As[buf];
    const bf16* bs = Bs[buf];

#pragma unroll
    for (int kk = 0; kk < 2; ++kk) {
      const int kc = kk ? kc1 : kc0;
      bf16x8 af[4], bfr[4];
#pragma unroll
      for (int mt = 0; mt < 4; ++mt)
        af[mt] = *(const bf16x8*)&as[(wm + mt * 16 + r) * GBK + kc];
#pragma unroll
      for (int nt = 0; nt < 4; ++nt)
        bfr[nt] = *(const bf16x8*)&bs[(wn + nt * 16 + r) * GBK + kc];
#pragma unroll
      for (int mt = 0; mt < 4; ++mt)
#pragma unroll
        for (int nt = 0; nt < 4; ++nt)
          acc[mt][nt] = __builtin_amdgcn_mfma_f32_16x16x32_bf16(
              af[mt], bfr[nt], acc[mt][nt], 0, 0, 0);
    }
    __builtin_amdgcn_s_barrier();
    buf ^= 1;
  }

#pragma unroll
  for (int mt = 0; mt < 4; ++mt)
#pragma unroll
    for (int nt = 0; nt < 4; ++nt)
#pragma unroll
      for (int k = 0; k < 4; ++k) {
        int row = r0 + row0 + wm + mt * 16 + q * 4 + k;
        int col = col0 + wn + nt * 16 + r;
        dst[(size_t)row * N_COLS + col] = acc[mt][nt][k];
      }
}

// ---------------------------------------------------------------------------
// Kernel 4: out = sum of S partial planes, f32x4 vectorized.
// ---------------------------------------------------------------------------
__global__ void reduce_addN(const float* __restrict__ P,
                            float* __restrict__ out, int segs) {
  size_t i = (size_t)blockIdx.x * blockDim.x + threadIdx.x;
  const f32x4* p = (const f32x4*)P;
  const size_t plane = (size_t)M_ROWS * N_COLS / 4;
  f32x4 a = p[i];
  for (int s = 1; s < segs; ++s) a += p[(size_t)s * plane + i];
  ((f32x4*)out)[i] = a;
}

// ---------------------------------------------------------------------------
// Fallback (ws too small — not expected; SL=4096 confirmed in R9/R10).
// ---------------------------------------------------------------------------
__global__ __launch_bounds__(256) void kan_fused_fallback(
    const float* __restrict__ x, const float* __restrict__ bw,
    const float* __restrict__ sw, const float* __restrict__ sc,
    float* __restrict__ out) {
  __shared__ bf16 As[64 * BK];
  __shared__ bf16 Bs[128 * BK];
  const int tid  = threadIdx.x;
  const int lane = tid & 63;
  const int w    = tid >> 6;
  const int col0 = blockIdx.x * 128;
  const int row0 = blockIdx.y * 64;
  const int srow = tid >> 2, sq = tid & 3;
  const int r = lane & 15, q = lane >> 4, wn = w * 32;

  f32x4 acc[4][2];
#pragma unroll
  for (int mt = 0; mt < 4; ++mt)
#pragma unroll
    for (int nt = 0; nt < 2; ++nt) acc[mt][nt] = f32x4{0,0,0,0};

  for (int kt = 0; kt < KT_CNT; ++kt) {
    if (kt < 32) {
      const int cc = sq * 8;
      const float4* xp = (const float4*)(x + (size_t)(row0+srow)*IN_F + kt*BK + cc);
      float4 a = xp[0], b4 = xp[1];
      float xv[8] = {a.x,a.y,a.z,a.w,b4.x,b4.y,b4.z,b4.w};
      bf16x8 av;
#pragma unroll
      for (int j = 0; j < 8; ++j) av[j] = (bf16)(xv[j] / (1.0f + __expf(-xv[j])));
      *(bf16x8*)&As[srow * BK + cc] = av;
#pragma unroll
      for (int h = 0; h < 2; ++h) {
        const float4* bp = (const float4*)(bw + (size_t)(col0+h*64+srow)*IN_F + kt*BK + cc);
        float4 c0 = bp[0], c1 = bp[1];
        float bv[8] = {c0.x,c0.y,c0.z,c0.w,c1.x,c1.y,c1.z,c1.w};
        bf16x8 bb;
#pragma unroll
        for (int j = 0; j < 8; ++j) bb[j] = (bf16)bv[j];
        *(bf16x8*)&Bs[(h*64+srow)*BK + cc] = bb;
      }
    } else {
      const int i = (kt - 32) * 4 + sq;
      float xv = x[(size_t)(row0+srow)*IN_F + i];
      float w8[8]; bases8(xv, w8);
      bf16x8 av;
#pragma unroll
      for (int j = 0; j < 8; ++j) av[j] = (bf16)w8[j];
      *(bf16x8*)&As[srow * BK + sq * 8] = av;
#pragma unroll
      for (int h = 0; h < 2; ++h) {
        const int o = col0 + h*64 + srow;
        float s1 = sc[(size_t)o*IN_F + i];
        const float4* sp = (const float4*)(sw + ((size_t)o*IN_F + i)*8);
        float4 c0 = sp[0], c1 = sp[1];
        float wv[8] = {c0.x,c0.y,c0.z,c0.w,c1.x,c1.y,c1.z,c1.w};
        bf16x8 bb;
#pragma unroll
        for (int j = 0; j < 8; ++j) bb[j] = (bf16)(wv[j]*s1);
        *(bf16x8*)&Bs[(h*64+srow)*BK + sq*8] = bb;
      }
    }
    __syncthreads();
    bf16x8 af[4], bfr[2];
#pragma unroll
    for (int mt = 0; mt < 4; ++mt)
      af[mt] = *(const bf16x8*)&As[(mt*16+r)*BK + q*8];
#pragma unroll
    for (int nt = 0; nt < 2; ++nt)
      bfr[nt] = *(const bf16x8*)&Bs[(wn+nt*16+r)*BK + q*8];
#pragma unroll
    for (int mt = 0; mt < 4; ++mt)
#pragma unroll
      for (int nt = 0; nt < 2; ++nt)
        acc[mt][nt] = __builtin_amdgcn_mfma_f32_16x16x32_bf16(af[mt], bfr[nt], acc[mt][nt], 0,0,0);
    __syncthreads();
  }
#pragma unroll
  for (int mt = 0; mt < 4; ++mt)
#pragma unroll
    for (int nt = 0; nt < 2; ++nt)
#pragma unroll
      for (int k = 0; k < 4; ++k)
        out[(size_t)(row0+mt*16+q*4+k)*N_COLS + col0+wn+nt*16+r] = acc[mt][nt][k];
}

extern "C" void kernel_launch(void* const* d_in, const int* in_sizes, int n_in,
                              void* d_out, int out_size, void* d_ws, size_t ws_size,
                              hipStream_t stream) {
  const float* x    = (const float*)d_in[0];
  const float* bw   = (const float*)d_in[1];
  const float* sw   = (const float*)d_in[2];
  const float* sc   = (const float*)d_in[3];
  float* out = (float*)d_out;

  const size_t BT_BYTES  = (size_t)N_COLS * K2 * sizeof(bf16);   // 18.9 MB
  const size_t ROW_BYTES = (size_t)K2 * sizeof(bf16);            // 18 KB
  const size_t A_BYTES   = (size_t)M_ROWS * ROW_BYTES;           // 75.5 MB
  const size_t OUT_BYTES = (size_t)M_ROWS * N_COLS * sizeof(float); // 16.8 MB

  // Split-K ladder: S=4 (full chip) -> 3 -> 2; kt_seg stays even (36/48/72).
  int S = 0;
  for (int c = 4; c >= 2; --c)
    if (GKT % c == 0 && ((GKT / c) % 2 == 0) &&
        BT_BYTES + A_BYTES + (size_t)c * OUT_BYTES <= ws_size) {
      S = c; break;
    }

  if (S >= 2) {
    bf16*  BT    = (bf16*)d_ws;
    bf16*  Aslab = BT + (size_t)N_COLS * K2;
    float* P     = (float*)((char*)d_ws + BT_BYTES + A_BYTES);
    prep<<<(M_ROWS * IN_F) / 256 + (N_COLS * IN_F) / 256, 256, 0, stream>>>(
        x, bw, sw, sc, Aslab, BT);
    gemm256_pl<<<S * 64, 512, 0, stream>>>(Aslab, BT, P, GKT / S);
    reduce_addN<<<(M_ROWS * N_COLS) / (4 * 256), 256, 0, stream>>>(P, out, S);
  } else {
    int SL = 0;
    for (int cand = 4096; cand >= 128; cand >>= 1)
      if (BT_BYTES + (size_t)cand * ROW_BYTES <= ws_size) { SL = cand; break; }
    if (SL) {
      bf16* BT    = (bf16*)d_ws;
      bf16* Aslab = BT + (size_t)N_COLS * K2;
      make_bt<<<(N_COLS * IN_F) / 256, 256, 0, stream>>>(bw, sw, sc, BT);
      for (int r0 = 0; r0 < M_ROWS; r0 += SL) {
        expand_a<<<(SL * IN_F) / 256, 256, 0, stream>>>(x, Aslab, r0);
        gemm_fused<<<(SL / 128) * (N_COLS / 128), 256, 0, stream>>>(
            Aslab, BT, out, out, r0, SL / 128, GKT);
      }
    } else {
      kan_fused_fallback<<<dim3(N_COLS / 128, M_ROWS / 64), 256, 0, stream>>>(
          x, bw, sw, sc, out);
    }
  }
  (void)in_sizes; (void)n_in; (void)out_size;
}

// Round 6
// 211.554 us; speedup vs baseline: 1.2575x; 1.2575x over previous
//
#include <hip/hip_runtime.h>
#include <hip/hip_bf16.h>
#include <cstdint>
#include <cstddef>

#define AS1 __attribute__((address_space(1)))
#define AS3 __attribute__((address_space(3)))

typedef __bf16 bf16;
typedef __bf16 bf16x4 __attribute__((ext_vector_type(4)));
typedef __bf16 bf16x8 __attribute__((ext_vector_type(8)));
typedef float f32x4 __attribute__((ext_vector_type(4)));

static constexpr int M_ROWS = 4096;
static constexpr int N_COLS = 1024;
static constexpr int IN_F   = 1024;
static constexpr int K2     = IN_F * 9;   // 9216: [silu(x) | 8 bases per i]
static constexpr int BK     = 32;         // fallback K-step
static constexpr int KT_CNT = K2 / BK;    // 288 (fallback)

static constexpr int GBK = 64;            // gemm K-step: rows are 128 B = 32 banks
static constexpr int GKT = K2 / GBK;      // 144

// Interface (R8 beacon): inputs f32, dict order, sizes in elements, out f32.

// Closed-form cardinal cubic B-spline over uniform knots t[j] = -2.2 + 0.4*j.
__device__ __forceinline__ void bases8(float x, float w8[8]) {
  float mf = x * 2.5f + 5.5f;           // (x - t0) / h
  int   m  = (int)floorf(mf);
  float u  = mf - (float)m;
  float u2 = u * u, u3 = u2 * u;
  float omu = 1.0f - u;
  const float s = 1.0f / 6.0f;
  float p0 = u3 * s;
  float p1 = (-3.f*u3 + 3.f*u2 + 3.f*u + 1.f) * s;
  float p2 = (3.f*u3 - 6.f*u2 + 4.f) * s;
  float p3 = omu * omu * omu * s;
  bool in = (m >= 0) && (m < 11);
#pragma unroll
  for (int j = 0; j < 8; ++j) {
    float v = 0.0f;
    v = (j == m)     ? p0 : v;
    v = (j == m - 1) ? p1 : v;
    v = (j == m - 2) ? p2 : v;
    v = (j == m - 3) ? p3 : v;
    w8[j] = in ? v : 0.0f;
  }
}

// ---------------------------------------------------------------------------
// Kernel 1 (R17): vectorized fused prep. 4 elements/thread, float4 in,
// bf16x4/bf16x8 out (G13: scalar bf16 paths are ~2-2.5x slower).
// Blocks [0, 4096): expand A (1M threads x 4 elems).
// Blocks [4096, 5120): build BT (256K threads x 4 elems).
// ---------------------------------------------------------------------------
__global__ __launch_bounds__(256) void prep4(
    const float* __restrict__ x, const float* __restrict__ bw,
    const float* __restrict__ sw, const float* __restrict__ sc,
    bf16* __restrict__ A, bf16* __restrict__ BT) {
  const int bid = blockIdx.x;
  if (bid < (M_ROWS * IN_F) / (4 * 256)) {
    // ---- expand: row b, 4 consecutive i ----
    const int t  = bid * 256 + threadIdx.x;       // 4-elem group index
    const int b  = t >> 8;                        // row (1024/4 groups/row)
    const int i0 = (t & 255) * 4;
    const float4 xv4 = *(const float4*)(x + (size_t)b * IN_F + i0);
    const float xs[4] = {xv4.x, xv4.y, xv4.z, xv4.w};

    bf16x4 sil;
    bf16* arow = A + (size_t)b * K2;
#pragma unroll
    for (int j = 0; j < 4; ++j) {
      float xv = xs[j];
      sil[j] = (bf16)(xv / (1.0f + __expf(-xv)));
      float w8[8];
      bases8(xv, w8);
      bf16x8 outv;
#pragma unroll
      for (int k = 0; k < 8; ++k) outv[k] = (bf16)w8[k];
      *(bf16x8*)(arow + IN_F + (size_t)(i0 + j) * 8) = outv;
    }
    *(bf16x4*)(arow + i0) = sil;
  } else {
    // ---- make_bt: row o, 4 consecutive i ----
    const int t  = (bid - (M_ROWS * IN_F) / (4 * 256)) * 256 + threadIdx.x;
    const int o  = t >> 8;
    const int i0 = (t & 255) * 4;
    const float4 bv4 = *(const float4*)(bw + (size_t)o * IN_F + i0);
    const float4 sc4 = *(const float4*)(sc + (size_t)o * IN_F + i0);
    const float bs[4] = {bv4.x, bv4.y, bv4.z, bv4.w};
    const float ss[4] = {sc4.x, sc4.y, sc4.z, sc4.w};

    bf16x4 base;
    bf16* brow = BT + (size_t)o * K2;
#pragma unroll
    for (int j = 0; j < 4; ++j) {
      base[j] = (bf16)bs[j];
      const float4* swp = (const float4*)(sw + ((size_t)o * IN_F + i0 + j) * 8);
      float4 a = swp[0], c = swp[1];
      float wv[8] = {a.x, a.y, a.z, a.w, c.x, c.y, c.z, c.w};
      bf16x8 r;
#pragma unroll
      for (int k = 0; k < 8; ++k) r[k] = (bf16)(wv[k] * ss[j]);
      *(bf16x8*)(brow + IN_F + (size_t)(i0 + j) * 8) = r;
    }
    *(bf16x4*)(brow + i0) = base;
  }
}

// Scalar bodies kept for the slab fallback path.
__device__ __forceinline__ void expand_body(const float* __restrict__ x,
                                            bf16* __restrict__ A, int gid, int r0) {
  int b = gid >> 10;
  int i = gid & 1023;
  float xv = x[(size_t)r0 * IN_F + (size_t)gid];
  A[(size_t)b * K2 + i] = (bf16)(xv / (1.0f + __expf(-xv)));
  float w8[8];
  bases8(xv, w8);
  bf16x8 outv;
#pragma unroll
  for (int j = 0; j < 8; ++j) outv[j] = (bf16)w8[j];
  *(bf16x8*)(A + (size_t)b * K2 + IN_F + (size_t)i * 8) = outv;
}

__device__ __forceinline__ void makebt_body(const float* __restrict__ bw,
                                            const float* __restrict__ sw,
                                            const float* __restrict__ sc,
                                            bf16* __restrict__ BT, int gid) {
  int o = gid >> 10;
  int i = gid & 1023;
  BT[(size_t)o * K2 + i] = (bf16)bw[gid];
  float scale = sc[gid];
  const float4* swp = (const float4*)(sw + (size_t)gid * 8);
  float4 a = swp[0], b4 = swp[1];
  float wv[8] = {a.x, a.y, a.z, a.w, b4.x, b4.y, b4.z, b4.w};
  bf16x8 r;
#pragma unroll
  for (int j = 0; j < 8; ++j) r[j] = (bf16)(wv[j] * scale);
  *(bf16x8*)(BT + (size_t)o * K2 + IN_F + (size_t)i * 8) = r;
}

__global__ void expand_a(const float* __restrict__ x, bf16* __restrict__ A, int r0) {
  expand_body(x, A, blockIdx.x * blockDim.x + threadIdx.x, r0);
}
__global__ void make_bt(const float* __restrict__ bw, const float* __restrict__ sw,
                        const float* __restrict__ sc, bf16* __restrict__ BT) {
  makebt_body(bw, sw, sc, BT, blockIdx.x * blockDim.x + threadIdx.x);
}

// ---------------------------------------------------------------------------
// Kernel 3 (R15 VERBATIM — best measured 80.5 µs / 957 TF / MfmaUtil 38%).
// R16's phase-early register pipeline regressed to 145 µs (112 fragment
// VGPRs -> spills); reverted. 8-phase schedule: per K-tile 4 phases; phase =
// {ds_reads for quadrant | stage 1 half-tile | barrier | lgkmcnt(0)+
// sched_barrier | setprio(1) 16 MFMA setprio(0) | barrier}. ONE vmcnt(2)
// per tile at P3. Swizzle chunk^=(row&7) both sides (0 conflicts measured).
// Split-K x4, XCD map b&15 (A pinned per XCD).
// ---------------------------------------------------------------------------
__global__ __launch_bounds__(512, 2) void gemm256_8p(
    const bf16* __restrict__ A, const bf16* __restrict__ BT,
    float* __restrict__ P, int kt_seg) {
  __shared__ bf16 As[2][256 * GBK];   // 2 x 32 KB
  __shared__ bf16 Bs[2][256 * GBK];   // 2 x 32 KB  (128 KB)

  const int tid  = threadIdx.x;
  const int lane = tid & 63;
  const int w    = tid >> 6;          // 0..7

  const int b     = blockIdx.x;
  const int mtile = b & 15;           // XCD = b&7 = mtile&7 -> A pinned
  const int np    = (b >> 4) & 3;
  const int seg   = b >> 6;
  const int row0  = mtile * 256;
  const int col0  = np * 256;
  const int kt0   = seg * kt_seg;
  float* __restrict__ dst = P + (size_t)seg * M_ROWS * N_COLS;

  const int srow = lane >> 3;
  const int sch  = ((lane & 7) ^ srow) * 8;

  const int r  = lane & 15;
  const int q  = lane >> 4;
  const int wm = (w >> 2) * 128;
  const int wn = (w & 3) * 64;
  const int kc0 = ((0 + q) ^ (r & 7)) * 8;
  const int kc1 = ((4 + q) ^ (r & 7)) * 8;

  const bf16* aB = A  + (size_t)row0 * K2;
  const bf16* bB = BT + (size_t)col0 * K2;

  f32x4 acc[8][4];
#pragma unroll
  for (int mt = 0; mt < 8; ++mt)
#pragma unroll
    for (int nt = 0; nt < 4; ++nt)
      acc[mt][nt] = f32x4{0.f, 0.f, 0.f, 0.f};

  auto stageA = [&](int sbuf, int h, int kt) {
#pragma unroll
    for (int t8 = 0; t8 < 2; ++t8) {
      const int rg = h * 128 + w * 16 + t8 * 8;
      const bf16* ga = aB + (size_t)(rg + srow) * K2 + kt * GBK + sch;
      __builtin_amdgcn_global_load_lds((const AS1 void*)ga,
                                       (AS3 void*)&As[sbuf][rg * GBK], 16, 0, 0);
    }
  };
  auto stageB = [&](int sbuf, int h, int kt) {
#pragma unroll
    for (int t8 = 0; t8 < 2; ++t8) {
      const int rg = h * 128 + w * 16 + t8 * 8;
      const bf16* gb = bB + (size_t)(rg + srow) * K2 + kt * GBK + sch;
      __builtin_amdgcn_global_load_lds((const AS1 void*)gb,
                                       (AS3 void*)&Bs[sbuf][rg * GBK], 16, 0, 0);
    }
  };

  // Prologue: tile0 fully + tile1's A-lo (= steady-state P3(t-1) slot).
  stageA(0, 0, kt0); stageA(0, 1, kt0);
  stageB(0, 0, kt0); stageB(0, 1, kt0);
  if (kt_seg > 1) stageA(1, 0, kt0 + 1);
  if (kt_seg > 1) asm volatile("s_waitcnt vmcnt(2)" ::: "memory");
  else            asm volatile("s_waitcnt vmcnt(0)" ::: "memory");
  __builtin_amdgcn_s_barrier();

  bf16x8 af[4][2], bfr[4][2];

  for (int t = 0; t < kt_seg; ++t) {
    const int buf = t & 1, nbuf = buf ^ 1;
    const bf16* as = As[buf];
    const bf16* bs = Bs[buf];
    const bool sN = (t + 1 < kt_seg);   // stage tile t+1 exists

    // ---- P0: reads af(mt0-3)+bfr(nt0-1) [12]; stage(t+1, A-hi); Q0 ----
#pragma unroll
    for (int j = 0; j < 4; ++j) {
      const bf16* ar = &as[(wm + j * 16 + r) * GBK];
      af[j][0] = *(const bf16x8*)&ar[kc0];
      af[j][1] = *(const bf16x8*)&ar[kc1];
    }
#pragma unroll
    for (int j = 0; j < 2; ++j) {
      const bf16* br = &bs[(wn + j * 16 + r) * GBK];
      bfr[j][0] = *(const bf16x8*)&br[kc0];
      bfr[j][1] = *(const bf16x8*)&br[kc1];
    }
    if (sN) stageA(nbuf, 1, kt0 + t + 1);
    asm volatile("s_waitcnt lgkmcnt(8)" ::: "memory");
    __builtin_amdgcn_s_barrier();
    asm volatile("s_waitcnt lgkmcnt(0)" ::: "memory");
    __builtin_amdgcn_sched_barrier(0);
    __builtin_amdgcn_s_setprio(1);
#pragma unroll
    for (int j = 0; j < 4; ++j)
#pragma unroll
      for (int n = 0; n < 2; ++n) {
        acc[j][n] = __builtin_amdgcn_mfma_f32_16x16x32_bf16(af[j][0], bfr[n][0], acc[j][n], 0, 0, 0);
        acc[j][n] = __builtin_amdgcn_mfma_f32_16x16x32_bf16(af[j][1], bfr[n][1], acc[j][n], 0, 0, 0);
      }
    __builtin_amdgcn_s_setprio(0);
    __builtin_amdgcn_s_barrier();

    // ---- P1: reads bfr(nt2-3) [4]; stage(t+1, B-lo); Q1 ----
#pragma unroll
    for (int j = 0; j < 2; ++j) {
      const bf16* br = &bs[(wn + (2 + j) * 16 + r) * GBK];
      bfr[2 + j][0] = *(const bf16x8*)&br[kc0];
      bfr[2 + j][1] = *(const bf16x8*)&br[kc1];
    }
    if (sN) stageB(nbuf, 0, kt0 + t + 1);
    __builtin_amdgcn_s_barrier();
    asm volatile("s_waitcnt lgkmcnt(0)" ::: "memory");
    __builtin_amdgcn_sched_barrier(0);
    __builtin_amdgcn_s_setprio(1);
#pragma unroll
    for (int j = 0; j < 4; ++j)
#pragma unroll
      for (int n = 0; n < 2; ++n) {
        acc[j][2 + n] = __builtin_amdgcn_mfma_f32_16x16x32_bf16(af[j][0], bfr[2 + n][0], acc[j][2 + n], 0, 0, 0);
        acc[j][2 + n] = __builtin_amdgcn_mfma_f32_16x16x32_bf16(af[j][1], bfr[2 + n][1], acc[j][2 + n], 0, 0, 0);
      }
    __builtin_amdgcn_s_setprio(0);
    __builtin_amdgcn_s_barrier();

    // ---- P2: reads af(mt4-7) [8]; stage(t+1, B-hi); Q2 ----
#pragma unroll
    for (int j = 0; j < 4; ++j) {
      const bf16* ar = &as[(wm + (4 + j) * 16 + r) * GBK];
      af[j][0] = *(const bf16x8*)&ar[kc0];
      af[j][1] = *(const bf16x8*)&ar[kc1];
    }
    if (sN) stageB(nbuf, 1, kt0 + t + 1);
    __builtin_amdgcn_s_barrier();
    asm volatile("s_waitcnt lgkmcnt(0)" ::: "memory");
    __builtin_amdgcn_sched_barrier(0);
    __builtin_amdgcn_s_setprio(1);
#pragma unroll
    for (int j = 0; j < 4; ++j)
#pragma unroll
      for (int n = 0; n < 2; ++n) {
        acc[4 + j][n] = __builtin_amdgcn_mfma_f32_16x16x32_bf16(af[j][0], bfr[n][0], acc[4 + j][n], 0, 0, 0);
        acc[4 + j][n] = __builtin_amdgcn_mfma_f32_16x16x32_bf16(af[j][1], bfr[n][1], acc[4 + j][n], 0, 0, 0);
      }
    __builtin_amdgcn_s_setprio(0);
    __builtin_amdgcn_s_barrier();

    // ---- P3: no reads; stage(t+2, A-lo) into freed buf; vmcnt; Q3 ----
    if (t + 2 < kt_seg) stageA(buf, 0, kt0 + t + 2);
    if (sN) {
      if (t + 2 < kt_seg) asm volatile("s_waitcnt vmcnt(2)" ::: "memory");
      else                asm volatile("s_waitcnt vmcnt(0)" ::: "memory");
    }
    __builtin_amdgcn_s_barrier();
    __builtin_amdgcn_s_setprio(1);
#pragma unroll
    for (int j = 0; j < 4; ++j)
#pragma unroll
      for (int n = 0; n < 2; ++n) {
        acc[4 + j][2 + n] = __builtin_amdgcn_mfma_f32_16x16x32_bf16(af[j][0], bfr[2 + n][0], acc[4 + j][2 + n], 0, 0, 0);
        acc[4 + j][2 + n] = __builtin_amdgcn_mfma_f32_16x16x32_bf16(af[j][1], bfr[2 + n][1], acc[4 + j][2 + n], 0, 0, 0);
      }
    __builtin_amdgcn_s_setprio(0);
    __builtin_amdgcn_s_barrier();
  }

  // f32 epilogue: C/D layout col = lane&15, row = (lane>>4)*4 + reg
#pragma unroll
  for (int mt = 0; mt < 8; ++mt)
#pragma unroll
    for (int nt = 0; nt < 4; ++nt)
#pragma unroll
      for (int k = 0; k < 4; ++k) {
        int row = row0 + wm + mt * 16 + q * 4 + k;
        int col = col0 + wn + nt * 16 + r;
        dst[(size_t)row * N_COLS + col] = acc[mt][nt][k];
      }
}

// ---------------------------------------------------------------------------
// Kernel 3b (R13's 128x128 gemm, kept for fallback slab path).
// ---------------------------------------------------------------------------
__global__ __launch_bounds__(256, 2) void gemm_fused(
    const bf16* __restrict__ A, const bf16* __restrict__ BT,
    float* __restrict__ d0, float* __restrict__ d1,
    int r0, int mt_cnt, int kt_seg) {
  __shared__ bf16 As[2][128 * GBK];
  __shared__ bf16 Bs[2][128 * GBK];

  const int tid  = threadIdx.x;
  const int lane = tid & 63;
  const int w    = tid >> 6;

  const int bps = mt_cnt * 8;
  int b   = blockIdx.x;
  const int seg = b / bps;
  b -= seg * bps;
  const int row0 = (b % mt_cnt) * 128;
  const int col0 = (b / mt_cnt) * 128;
  float* __restrict__ dst = seg ? d1 : d0;
  const int kt0 = seg * kt_seg;

  const int srow = lane >> 3;
  const int sch  = ((lane & 7) ^ srow) * 8;
  const int r  = lane & 15;
  const int q  = lane >> 4;
  const int wm = (w >> 1) * 64;
  const int wn = (w & 1) * 64;
  const int kc0 = ((0 + q) ^ (r & 7)) * 8;
  const int kc1 = ((4 + q) ^ (r & 7)) * 8;

  const bf16* aB = A  + (size_t)row0 * K2;
  const bf16* bB = BT + (size_t)col0 * K2;

  f32x4 acc[4][4];
#pragma unroll
  for (int mt = 0; mt < 4; ++mt)
#pragma unroll
    for (int nt = 0; nt < 4; ++nt)
      acc[mt][nt] = f32x4{0.f, 0.f, 0.f, 0.f};

  auto stage = [&](int sbuf, int kt) {
#pragma unroll
    for (int t = 0; t < 4; ++t) {
      const int rg = w * 32 + t * 8;
      const bf16* ga = aB + (size_t)(rg + srow) * K2 + kt * GBK + sch;
      __builtin_amdgcn_global_load_lds((const AS1 void*)ga,
                                       (AS3 void*)&As[sbuf][rg * GBK], 16, 0, 0);
      const bf16* gb = bB + (size_t)(rg + srow) * K2 + kt * GBK + sch;
      __builtin_amdgcn_global_load_lds((const AS1 void*)gb,
                                       (AS3 void*)&Bs[sbuf][rg * GBK], 16, 0, 0);
    }
  };

  stage(0, kt0);
  int buf = 0;
  for (int i = 0; i < kt_seg; ++i) {
    if (i + 1 < kt_seg) {
      stage(buf ^ 1, kt0 + i + 1);
      asm volatile("s_waitcnt vmcnt(8)" ::: "memory");
    } else {
      asm volatile("s_waitcnt vmcnt(0)" ::: "memory");
    }
    __builtin_amdgcn_s_barrier();
    __builtin_amdgcn_sched_barrier(0);

    const bf16* as = As[buf];
    const bf16* bs = Bs[buf];

#pragma unroll
    for (int kk = 0; kk < 2; ++kk) {
      const int kc = kk ? kc1 : kc0;
      bf16x8 af[4], bfr[4];
#pragma unroll
      for (int mt = 0; mt < 4; ++mt)
        af[mt] = *(const bf16x8*)&as[(wm + mt * 16 + r) * GBK + kc];
#pragma unroll
      for (int nt = 0; nt < 4; ++nt)
        bfr[nt] = *(const bf16x8*)&bs[(wn + nt * 16 + r) * GBK + kc];
#pragma unroll
      for (int mt = 0; mt < 4; ++mt)
#pragma unroll
        for (int nt = 0; nt < 4; ++nt)
          acc[mt][nt] = __builtin_amdgcn_mfma_f32_16x16x32_bf16(
              af[mt], bfr[nt], acc[mt][nt], 0, 0, 0);
    }
    __builtin_amdgcn_s_barrier();
    buf ^= 1;
  }

#pragma unroll
  for (int mt = 0; mt < 4; ++mt)
#pragma unroll
    for (int nt = 0; nt < 4; ++nt)
#pragma unroll
      for (int k = 0; k < 4; ++k) {
        int row = r0 + row0 + wm + mt * 16 + q * 4 + k;
        int col = col0 + wn + nt * 16 + r;
        dst[(size_t)row * N_COLS + col] = acc[mt][nt][k];
      }
}

// ---------------------------------------------------------------------------
// Kernel 4 (R17): grid-stride f32x4 reduce, 2048 blocks, S=4 unrolled.
// ---------------------------------------------------------------------------
__global__ __launch_bounds__(256) void reduce_addN(
    const float* __restrict__ P, float* __restrict__ out, int segs) {
  const size_t plane = (size_t)M_ROWS * N_COLS / 4;
  const f32x4* p = (const f32x4*)P;
  f32x4* o = (f32x4*)out;
  const size_t stride = (size_t)gridDim.x * blockDim.x;
  for (size_t i = (size_t)blockIdx.x * blockDim.x + threadIdx.x; i < plane;
       i += stride) {
    if (segs == 4) {
      f32x4 a = p[i] + p[plane + i];
      f32x4 c = p[2 * plane + i] + p[3 * plane + i];
      o[i] = a + c;
    } else {
      f32x4 a = p[i];
      for (int s = 1; s < segs; ++s) a += p[(size_t)s * plane + i];
      o[i] = a;
    }
  }
}

// ---------------------------------------------------------------------------
// Fallback (ws too small — not expected; SL=4096 confirmed in R9/R10).
// ---------------------------------------------------------------------------
__global__ __launch_bounds__(256) void kan_fused_fallback(
    const float* __restrict__ x, const float* __restrict__ bw,
    const float* __restrict__ sw, const float* __restrict__ sc,
    float* __restrict__ out) {
  __shared__ bf16 As[64 * BK];
  __shared__ bf16 Bs[128 * BK];
  const int tid  = threadIdx.x;
  const int lane = tid & 63;
  const int w    = tid >> 6;
  const int col0 = blockIdx.x * 128;
  const int row0 = blockIdx.y * 64;
  const int srow = tid >> 2, sq = tid & 3;
  const int r = lane & 15, q = lane >> 4, wn = w * 32;

  f32x4 acc[4][2];
#pragma unroll
  for (int mt = 0; mt < 4; ++mt)
#pragma unroll
    for (int nt = 0; nt < 2; ++nt) acc[mt][nt] = f32x4{0,0,0,0};

  for (int kt = 0; kt < KT_CNT; ++kt) {
    if (kt < 32) {
      const int cc = sq * 8;
      const float4* xp = (const float4*)(x + (size_t)(row0+srow)*IN_F + kt*BK + cc);
      float4 a = xp[0], b4 = xp[1];
      float xv[8] = {a.x,a.y,a.z,a.w,b4.x,b4.y,b4.z,b4.w};
      bf16x8 av;
#pragma unroll
      for (int j = 0; j < 8; ++j) av[j] = (bf16)(xv[j] / (1.0f + __expf(-xv[j])));
      *(bf16x8*)&As[srow * BK + cc] = av;
#pragma unroll
      for (int h = 0; h < 2; ++h) {
        const float4* bp = (const float4*)(bw + (size_t)(col0+h*64+srow)*IN_F + kt*BK + cc);
        float4 c0 = bp[0], c1 = bp[1];
        float bv[8] = {c0.x,c0.y,c0.z,c0.w,c1.x,c1.y,c1.z,c1.w};
        bf16x8 bb;
#pragma unroll
        for (int j = 0; j < 8; ++j) bb[j] = (bf16)bv[j];
        *(bf16x8*)&Bs[(h*64+srow)*BK + cc] = bb;
      }
    } else {
      const int i = (kt - 32) * 4 + sq;
      float xv = x[(size_t)(row0+srow)*IN_F + i];
      float w8[8]; bases8(xv, w8);
      bf16x8 av;
#pragma unroll
      for (int j = 0; j < 8; ++j) av[j] = (bf16)w8[j];
      *(bf16x8*)&As[srow * BK + sq * 8] = av;
#pragma unroll
      for (int h = 0; h < 2; ++h) {
        const int o = col0 + h*64 + srow;
        float s1 = sc[(size_t)o*IN_F + i];
        const float4* sp = (const float4*)(sw + ((size_t)o*IN_F + i)*8);
        float4 c0 = sp[0], c1 = sp[1];
        float wv[8] = {c0.x,c0.y,c0.z,c0.w,c1.x,c1.y,c1.z,c1.w};
        bf16x8 bb;
#pragma unroll
        for (int j = 0; j < 8; ++j) bb[j] = (bf16)(wv[j]*s1);
        *(bf16x8*)&Bs[(h*64+srow)*BK + sq*8] = bb;
      }
    }
    __syncthreads();
    bf16x8 af[4], bfr[2];
#pragma unroll
    for (int mt = 0; mt < 4; ++mt)
      af[mt] = *(const bf16x8*)&As[(mt*16+r)*BK + q*8];
#pragma unroll
    for (int nt = 0; nt < 2; ++nt)
      bfr[nt] = *(const bf16x8*)&Bs[(wn+nt*16+r)*BK + q*8];
#pragma unroll
    for (int mt = 0; mt < 4; ++mt)
#pragma unroll
      for (int nt = 0; nt < 2; ++nt)
        acc[mt][nt] = __builtin_amdgcn_mfma_f32_16x16x32_bf16(af[mt], bfr[nt], acc[mt][nt], 0,0,0);
    __syncthreads();
  }
#pragma unroll
  for (int mt = 0; mt < 4; ++mt)
#pragma unroll
    for (int nt = 0; nt < 2; ++nt)
#pragma unroll
      for (int k = 0; k < 4; ++k)
        out[(size_t)(row0+mt*16+q*4+k)*N_COLS + col0+wn+nt*16+r] = acc[mt][nt][k];
}

extern "C" void kernel_launch(void* const* d_in, const int* in_sizes, int n_in,
                              void* d_out, int out_size, void* d_ws, size_t ws_size,
                              hipStream_t stream) {
  const float* x    = (const float*)d_in[0];
  const float* bw   = (const float*)d_in[1];
  const float* sw   = (const float*)d_in[2];
  const float* sc   = (const float*)d_in[3];
  float* out = (float*)d_out;

  const size_t BT_BYTES  = (size_t)N_COLS * K2 * sizeof(bf16);   // 18.9 MB
  const size_t ROW_BYTES = (size_t)K2 * sizeof(bf16);            // 18 KB
  const size_t A_BYTES   = (size_t)M_ROWS * ROW_BYTES;           // 75.5 MB
  const size_t OUT_BYTES = (size_t)M_ROWS * N_COLS * sizeof(float); // 16.8 MB

  // Split-K ladder: S=4 (full chip) -> 3 -> 2, whatever fits in ws.
  int S = 0;
  for (int c = 4; c >= 2; --c)
    if (GKT % c == 0 && BT_BYTES + A_BYTES + (size_t)c * OUT_BYTES <= ws_size) {
      S = c; break;
    }

  if (S >= 2) {
    bf16*  BT    = (bf16*)d_ws;
    bf16*  Aslab = BT + (size_t)N_COLS * K2;
    float* P     = (float*)((char*)d_ws + BT_BYTES + A_BYTES);
    prep4<<<(M_ROWS * IN_F) / (4 * 256) + (N_COLS * IN_F) / (4 * 256), 256, 0,
            stream>>>(x, bw, sw, sc, Aslab, BT);
    gemm256_8p<<<S * 64, 512, 0, stream>>>(Aslab, BT, P, GKT / S);
    reduce_addN<<<2048, 256, 0, stream>>>(P, out, S);
  } else {
    int SL = 0;
    for (int cand = 4096; cand >= 128; cand >>= 1)
      if (BT_BYTES + (size_t)cand * ROW_BYTES <= ws_size) { SL = cand; break; }
    if (SL) {
      bf16* BT    = (bf16*)d_ws;
      bf16* Aslab = BT + (size_t)N_COLS * K2;
      make_bt<<<(N_COLS * IN_F) / 256, 256, 0, stream>>>(bw, sw, sc, BT);
      for (int r0 = 0; r0 < M_ROWS; r0 += SL) {
        expand_a<<<(SL * IN_F) / 256, 256, 0, stream>>>(x, Aslab, r0);
        gemm_fused<<<(SL / 128) * (N_COLS / 128), 256, 0, stream>>>(
            Aslab, BT, out, out, r0, SL / 128, GKT);
      }
    } else {
      kan_fused_fallback<<<dim3(N_COLS / 128, M_ROWS / 64), 256, 0, stream>>>(
          x, bw, sw, sc, out);
    }
  }
  (void)in_sizes; (void)n_in; (void)out_size;
}